// Round 1
// baseline (1623.139 us; speedup 1.0000x reference)
//
#include <hip/hip_runtime.h>
#include <math.h>

#define NDIM 4096
#define CDIM 256
#define KD   32
#define BATCH 4
#define NBR  2
#define SCALE 0.17677669529663687f  // 1/sqrt(32)

// ---------------------------------------------------------------------------
// K1: conv1x1 GEMM  out[b][o][n] = sum_c W[o][c] * X[b][c][n] + bias[o]
// grid (N/64, O/32, B), block 256. Tiles: 32(O) x 64(N), K-step 32.
// ---------------------------------------------------------------------------
__global__ __launch_bounds__(256) void conv1x1_kernel(
    const float* __restrict__ W, const float* __restrict__ bias,
    const float* __restrict__ X, float* __restrict__ out, int O)
{
  __shared__ float Ws[32][33];   // +1 pad: avoid same-bank on Ws[o][kk] reads
  __shared__ float Xs[32][64];
  const int t = threadIdx.x;
  const int ntile = blockIdx.x * 64;
  const int otile = blockIdx.y * 32;
  const int b = blockIdx.z;
  const float* Xb = X + (size_t)b * CDIM * NDIM;
  float acc[2][4] = {};
  const int tn = (t & 15) * 4;   // 4 consecutive n
  const int to = (t >> 4) * 2;   // 2 consecutive o

  for (int k0 = 0; k0 < CDIM; k0 += 32) {
#pragma unroll
    for (int i = 0; i < 4; i++) {
      int e = t + i * 256, o = e >> 5, k = e & 31;
      Ws[o][k] = W[(size_t)(otile + o) * CDIM + k0 + k];
    }
#pragma unroll
    for (int i = 0; i < 8; i++) {
      int e = t + i * 256, k = e >> 6, n = e & 63;
      Xs[k][n] = Xb[(size_t)(k0 + k) * NDIM + ntile + n];
    }
    __syncthreads();
#pragma unroll
    for (int kk = 0; kk < 32; kk++) {
      float w0 = Ws[to][kk], w1 = Ws[to + 1][kk];
      float4 xv = *(const float4*)&Xs[kk][tn];
      acc[0][0] += w0 * xv.x; acc[0][1] += w0 * xv.y;
      acc[0][2] += w0 * xv.z; acc[0][3] += w0 * xv.w;
      acc[1][0] += w1 * xv.x; acc[1][1] += w1 * xv.y;
      acc[1][2] += w1 * xv.z; acc[1][3] += w1 * xv.w;
    }
    __syncthreads();
  }
  float b0 = bias[otile + to], b1 = bias[otile + to + 1];
  float* o0 = out + ((size_t)b * O + otile + to) * NDIM + ntile + tn;
  float* o1 = o0 + NDIM;
  float4 v0 = make_float4(acc[0][0] + b0, acc[0][1] + b0, acc[0][2] + b0, acc[0][3] + b0);
  float4 v1 = make_float4(acc[1][0] + b1, acc[1][1] + b1, acc[1][2] + b1, acc[1][3] + b1);
  *(float4*)o0 = v0;
  *(float4*)o1 = v1;
}

// ---------------------------------------------------------------------------
// K2: per-row softmax stats. L[n] = max_m s[n,m] + log(sum_m exp(s[n,m]-max))
// where s[n,m] = SCALE * sum_k f[k,n] g[k,m].
// grid (N/64, B, NBR), block 256. Thread: row n = t&63, m-quarter q = t>>6.
// ---------------------------------------------------------------------------
__global__ __launch_bounds__(256) void stats_kernel(
    const float* __restrict__ f, const float* __restrict__ g,
    float* __restrict__ L)
{
  __shared__ float gs[KD][64];
  __shared__ float red[64][4][2];
  const int t = threadIdx.x;
  const int ntile = blockIdx.x * 64;
  const int b = blockIdx.y, br = blockIdx.z;
  const size_t bb = (size_t)(br * BATCH + b);
  const float* fb = f + bb * KD * NDIM;
  const float* gb = g + bb * KD * NDIM;
  const int nl = t & 63, q = t >> 6;
  const int ng = ntile + nl;

  float fr[KD];
#pragma unroll
  for (int k = 0; k < KD; k++) fr[k] = fb[(size_t)k * NDIM + ng];

  float mrun = -1e30f, zrun = 0.f;
  for (int m0 = 0; m0 < NDIM; m0 += 64) {
    __syncthreads();
#pragma unroll
    for (int i = 0; i < 8; i++) {
      int e = t + i * 256, k = e >> 6, m = e & 63;
      gs[k][m] = gb[(size_t)k * NDIM + m0 + m];
    }
    __syncthreads();
#pragma unroll 4
    for (int j = 0; j < 16; j++) {
      int ml = q * 16 + j;
      float s = 0.f;
#pragma unroll
      for (int k = 0; k < KD; k++) s += fr[k] * gs[k][ml];
      s *= SCALE;
      float mnew = fmaxf(mrun, s);
      zrun = zrun * __expf(mrun - mnew) + __expf(s - mnew);
      mrun = mnew;
    }
  }
  red[nl][q][0] = mrun;
  red[nl][q][1] = zrun;
  __syncthreads();
  if (t < 64) {
    float M = -1e30f;
#pragma unroll
    for (int i = 0; i < 4; i++) M = fmaxf(M, red[t][i][0]);
    float Z = 0.f;
#pragma unroll
    for (int i = 0; i < 4; i++) Z += red[t][i][1] * __expf(red[t][i][0] - M);
    L[bb * NDIM + ntile + t] = M + logf(Z);
  }
}

// ---------------------------------------------------------------------------
// K3: apply. For m-tile of 64: acc[c][m] = sum_n h[c,n] * exp(s[n,m] - L[n]);
// out = gamma * acc + x. grid (N/64, B, NBR), block 512.
// Full C=256 per block; n processed in chunks of 32.
// ---------------------------------------------------------------------------
__global__ __launch_bounds__(512) void apply_kernel(
    const float* __restrict__ f, const float* __restrict__ g,
    const float* __restrict__ h, const float* __restrict__ L,
    const float* __restrict__ x1, const float* __restrict__ x2,
    const float* __restrict__ gamma1, const float* __restrict__ gamma2,
    float* __restrict__ out)
{
  __shared__ float hs[CDIM][33];  // h[c][n-chunk], +1 pad
  __shared__ float gs[KD][64];    // g[k][m-tile], staged once
  __shared__ float fs[KD][32];    // f[k][n-chunk]
  __shared__ float ps[32][68];    // P[n][m], +4 pad (keeps float4 alignment)
  __shared__ float Ls[32];
  const int t = threadIdx.x;
  const int mtile = blockIdx.x * 64;
  const int b = blockIdx.y, br = blockIdx.z;
  const size_t bb = (size_t)(br * BATCH + b);
  const float* fb = f + bb * KD * NDIM;
  const float* gb = g + bb * KD * NDIM;
  const float* hb = h + bb * CDIM * NDIM;
  const float* Lb = L + bb * NDIM;

  // stage g tile once (2048 elems / 512 thr)
#pragma unroll
  for (int i = 0; i < 4; i++) {
    int e = t + i * 512, k = e >> 6, m = e & 63;
    gs[k][m] = gb[(size_t)k * NDIM + mtile + m];
  }

  const int mq = t & 15;   // m = mq*4 (4 consecutive)
  const int cg = t >> 4;   // c = cg*8 (8 consecutive)
  const int pn = t & 31;   // P-row
  const int pmj = t >> 5;  // P m-group: m = pmj*4..+3
  float acc[8][4] = {};

  for (int n0 = 0; n0 < NDIM; n0 += 32) {
    __syncthreads();
    // stage h[c][n-chunk]: 8192 elems / 512 thr
#pragma unroll
    for (int i = 0; i < 16; i++) {
      int e = t + i * 512, c = e >> 5, n = e & 31;
      hs[c][n] = hb[(size_t)c * NDIM + n0 + n];
    }
    // stage f[k][n-chunk]: 1024 / 512
#pragma unroll
    for (int i = 0; i < 2; i++) {
      int e = t + i * 512, k = e >> 5, n = e & 31;
      fs[k][n] = fb[(size_t)k * NDIM + n0 + n];
    }
    if (t < 32) Ls[t] = Lb[n0 + t];
    __syncthreads();

    // compute P tile 32(n) x 64(m): each thread 4 P values
    {
      float s0 = 0, s1 = 0, s2 = 0, s3 = 0;
      int m = pmj * 4;
      for (int k = 0; k < KD; k++) {
        float fv = fs[k][pn];
        float4 gv = *(const float4*)&gs[k][m];
        s0 += fv * gv.x; s1 += fv * gv.y; s2 += fv * gv.z; s3 += fv * gv.w;
      }
      float Lv = Ls[pn];
      ps[pn][m + 0] = __expf(s0 * SCALE - Lv);
      ps[pn][m + 1] = __expf(s1 * SCALE - Lv);
      ps[pn][m + 2] = __expf(s2 * SCALE - Lv);
      ps[pn][m + 3] = __expf(s3 * SCALE - Lv);
    }
    __syncthreads();

    // PV: acc[c][m] += h[c][n] * P[n][m]
    for (int n = 0; n < 32; n++) {
      float4 pv = *(const float4*)&ps[n][mq * 4];
      float hv[8];
#pragma unroll
      for (int i = 0; i < 8; i++) hv[i] = hs[cg * 8 + i][n];
#pragma unroll
      for (int i = 0; i < 8; i++) {
        acc[i][0] += hv[i] * pv.x; acc[i][1] += hv[i] * pv.y;
        acc[i][2] += hv[i] * pv.z; acc[i][3] += hv[i] * pv.w;
      }
    }
  }

  // epilogue: out = gamma * acc + x
  const float gmv = (br == 0) ? gamma1[0] : gamma2[0];
  const float* xb = ((br == 0) ? x1 : x2) + (size_t)b * CDIM * NDIM;
  float* ob = out + bb * CDIM * NDIM;
#pragma unroll
  for (int i = 0; i < 8; i++) {
    int c = cg * 8 + i;
    size_t idx = (size_t)c * NDIM + mtile + mq * 4;
    float4 xv = *(const float4*)(xb + idx);
    float4 yv;
    yv.x = gmv * acc[i][0] + xv.x;
    yv.y = gmv * acc[i][1] + xv.y;
    yv.z = gmv * acc[i][2] + xv.z;
    yv.w = gmv * acc[i][3] + xv.w;
    *(float4*)(ob + idx) = yv;
  }
}

// ---------------------------------------------------------------------------
extern "C" void kernel_launch(void* const* d_in, const int* in_sizes, int n_in,
                              void* d_out, int out_size, void* d_ws, size_t ws_size,
                              hipStream_t stream) {
  const float* x1 = (const float*)d_in[0];
  const float* x2 = (const float*)d_in[1];
  const float* f_w = (const float*)d_in[2];
  const float* f_b = (const float*)d_in[3];
  const float* g_w = (const float*)d_in[4];
  const float* g_b = (const float*)d_in[5];
  const float* h1_w = (const float*)d_in[6];
  const float* h1_b = (const float*)d_in[7];
  const float* h2_w = (const float*)d_in[8];
  const float* h2_b = (const float*)d_in[9];
  const float* gamma1 = (const float*)d_in[10];
  const float* gamma2 = (const float*)d_in[11];
  float* out = (float*)d_out;

  float* ws = (float*)d_ws;
  const size_t fg_sz = (size_t)NBR * BATCH * KD * NDIM;   // 1,048,576 floats
  const size_t h_sz  = (size_t)NBR * BATCH * CDIM * NDIM; // 8,388,608 floats
  float* wf = ws;
  float* wg = wf + fg_sz;
  float* wh = wg + fg_sz;
  float* wL = wh + h_sz;                                  // 32,768 floats

  const size_t br_fg = (size_t)BATCH * KD * NDIM;
  const size_t br_h  = (size_t)BATCH * CDIM * NDIM;

  // projections (f,g shared weights across branches; h per-branch)
  conv1x1_kernel<<<dim3(64, 1, 4), 256, 0, stream>>>(f_w, f_b, x1, wf, KD);
  conv1x1_kernel<<<dim3(64, 1, 4), 256, 0, stream>>>(g_w, g_b, x1, wg, KD);
  conv1x1_kernel<<<dim3(64, 8, 4), 256, 0, stream>>>(h1_w, h1_b, x1, wh, CDIM);
  conv1x1_kernel<<<dim3(64, 1, 4), 256, 0, stream>>>(f_w, f_b, x2, wf + br_fg, KD);
  conv1x1_kernel<<<dim3(64, 1, 4), 256, 0, stream>>>(g_w, g_b, x2, wg + br_fg, KD);
  conv1x1_kernel<<<dim3(64, 8, 4), 256, 0, stream>>>(h2_w, h2_b, x2, wh + br_h, CDIM);

  // softmax row stats
  stats_kernel<<<dim3(64, 4, 2), 256, 0, stream>>>(wf, wg, wL);

  // apply attention + residual
  apply_kernel<<<dim3(64, 4, 2), 512, 0, stream>>>(wf, wg, wh, wL, x1, x2,
                                                   gamma1, gamma2, out);
}

// Round 2
// 354.584 us; speedup vs baseline: 4.5776x; 4.5776x over previous
//
#include <hip/hip_runtime.h>
#include <math.h>

#define NDIM 4096
#define CDIM 256
#define KD   32
#define SCALE 0.17677669529663687f  // 1/sqrt(32)
#define SHIFT 8.0f

typedef __attribute__((ext_vector_type(8))) short short8;  // 8 bf16 = 4 VGPRs
typedef __attribute__((ext_vector_type(4))) float f32x4;
typedef unsigned short u16;
typedef unsigned int u32;

__device__ __forceinline__ u32 f2bf(float x) {  // fp32 -> bf16 bits, RNE
  union { float f; u32 u; } v; v.f = x;
  return (v.u + 0x7FFFu + ((v.u >> 16) & 1u)) >> 16;
}

#define MFMA16(a, b, c) __builtin_amdgcn_mfma_f32_16x16x32_bf16((a), (b), (c), 0, 0, 0)

// ---------------------------------------------------------------------------
// cast fp32 -> bf16 (weights)
// ---------------------------------------------------------------------------
__global__ void cast_bf16_kernel(const float* __restrict__ in,
                                 u16* __restrict__ out, int n) {
  int i = blockIdx.x * 256 + threadIdx.x;
  if (i < n) out[i] = (u16)f2bf(in[i]);
}

// ---------------------------------------------------------------------------
// x[b][C][n] fp32 -> xT[bb][n][C] bf16  (so conv B-frags are contiguous in K=C)
// block 256, tile 64C x 64n, grid (64, 4, 8)
// ---------------------------------------------------------------------------
__global__ __launch_bounds__(256) void transpose_cast_kernel(
    const float* __restrict__ x1, const float* __restrict__ x2,
    u16* __restrict__ xt) {
  __shared__ float ts[64][68];  // row 272B: 16B-aligned cols, odd-word stride
  const int t = threadIdx.x;
  const int ntile = blockIdx.x * 64, Ctile = blockIdx.y * 64, z = blockIdx.z;
  const float* xb = ((z >> 2) ? x2 : x1) + (size_t)(z & 3) * CDIM * NDIM;
  u16* xtb = xt + (size_t)z * NDIM * CDIM;
  const int r = t >> 4, c4 = (t & 15) * 4;
#pragma unroll
  for (int i = 0; i < 4; i++) {
    float4 v = *(const float4*)&xb[(size_t)(Ctile + r + i * 16) * NDIM + ntile + c4];
    *(float4*)&ts[r + i * 16][c4] = v;
  }
  __syncthreads();
  const int n = t >> 2, Cg = (t & 3) * 16;
  u32 pk[8];
#pragma unroll
  for (int j = 0; j < 8; j++) {
    u32 lo = f2bf(ts[Cg + 2 * j][n]);
    u32 hi = f2bf(ts[Cg + 2 * j + 1][n]);
    pk[j] = lo | (hi << 16);
  }
  uint4* dst = (uint4*)&xtb[(size_t)(ntile + n) * CDIM + Ctile + Cg];
  dst[0] = make_uint4(pk[0], pk[1], pk[2], pk[3]);
  dst[1] = make_uint4(pk[4], pk[5], pk[6], pk[7]);
}

// ---------------------------------------------------------------------------
// conv f/g: outT[bb][n][32] = (W[32][256] @ x[.][C][n])^T + bias, via MFMA.
// block 256 (4 waves), tile 32o x 128n, grid (32, 8)
// ---------------------------------------------------------------------------
__global__ __launch_bounds__(256) void conv_fg_kernel(
    const u16* __restrict__ W, const float* __restrict__ bias,
    const u16* __restrict__ xt, u16* __restrict__ outT) {
  const int t = threadIdx.x, w = t >> 6, l = t & 63, li = l & 15, q = l >> 4;
  const int ntile = blockIdx.x * 128, bb = blockIdx.y;
  const u16* xtb = xt + (size_t)bb * NDIM * CDIM;
  u16* ob = outT + (size_t)bb * NDIM * KD;
  f32x4 zero4 = {0.f, 0.f, 0.f, 0.f};
  f32x4 acc[2][2];
  for (int i = 0; i < 2; i++) for (int j = 0; j < 2; j++) acc[i][j] = zero4;

  for (int k0 = 0; k0 < CDIM; k0 += 32) {
    short8 a0 = *(const short8*)&W[(size_t)(li) * CDIM + k0 + q * 8];
    short8 a1 = *(const short8*)&W[(size_t)(16 + li) * CDIM + k0 + q * 8];
    short8 b0 = *(const short8*)&xtb[(size_t)(ntile + (w * 2) * 16 + li) * CDIM + k0 + q * 8];
    short8 b1 = *(const short8*)&xtb[(size_t)(ntile + (w * 2 + 1) * 16 + li) * CDIM + k0 + q * 8];
    acc[0][0] = MFMA16(a0, b0, acc[0][0]);
    acc[0][1] = MFMA16(a0, b1, acc[0][1]);
    acc[1][0] = MFMA16(a1, b0, acc[1][0]);
    acc[1][1] = MFMA16(a1, b1, acc[1][1]);
  }
#pragma unroll
  for (int os = 0; os < 2; os++) {
    float bv[4];
#pragma unroll
    for (int reg = 0; reg < 4; reg++) bv[reg] = bias[os * 16 + q * 4 + reg];
#pragma unroll
    for (int ns = 0; ns < 2; ns++) {
      int n = ntile + (w * 2 + ns) * 16 + li;
      u32 p0 = f2bf(acc[os][ns][0] + bv[0]) | (f2bf(acc[os][ns][1] + bv[1]) << 16);
      u32 p1 = f2bf(acc[os][ns][2] + bv[2]) | (f2bf(acc[os][ns][3] + bv[3]) << 16);
      *(uint2*)&ob[(size_t)n * KD + os * 16 + q * 4] = make_uint2(p0, p1);
    }
  }
}

// ---------------------------------------------------------------------------
// conv h: outH[b][c][n] = W[256][256] @ x + bias, via MFMA.
// block 256 (4 waves), tile 64o x 64n, grid (64, 4, 4)
// ---------------------------------------------------------------------------
__global__ __launch_bounds__(256) void conv_h_kernel(
    const u16* __restrict__ W, const float* __restrict__ bias,
    const u16* __restrict__ xt, u16* __restrict__ outH) {
  const int t = threadIdx.x, w = t >> 6, l = t & 63, li = l & 15, q = l >> 4;
  const int ntile = blockIdx.x * 64;
  const int o0 = blockIdx.y * 64 + w * 16;
  const int b = blockIdx.z;
  const u16* xtb = xt + (size_t)b * NDIM * CDIM;
  u16* ob = outH + (size_t)b * CDIM * NDIM;
  f32x4 zero4 = {0.f, 0.f, 0.f, 0.f};
  f32x4 acc[4];
  for (int i = 0; i < 4; i++) acc[i] = zero4;

  for (int k0 = 0; k0 < CDIM; k0 += 32) {
    short8 a = *(const short8*)&W[(size_t)(o0 + li) * CDIM + k0 + q * 8];
#pragma unroll
    for (int ns = 0; ns < 4; ns++) {
      short8 bf = *(const short8*)&xtb[(size_t)(ntile + ns * 16 + li) * CDIM + k0 + q * 8];
      acc[ns] = MFMA16(a, bf, acc[ns]);
    }
  }
  float bv[4];
#pragma unroll
  for (int reg = 0; reg < 4; reg++) bv[reg] = bias[o0 + q * 4 + reg];
#pragma unroll
  for (int ns = 0; ns < 4; ns++) {
    int n = ntile + ns * 16 + li;
#pragma unroll
    for (int reg = 0; reg < 4; reg++) {
      int c = o0 + q * 4 + reg;
      ob[(size_t)c * NDIM + n] = (u16)f2bf(acc[ns][reg] + bv[reg]);
    }
  }
}

// ---------------------------------------------------------------------------
// stats: L[n] = SHIFT + log(sum_m exp(s[n,m]-SHIFT)), s = SCALE*(f^T g)
// block 256 (4 waves), n-tile 32, grid (128, 4, 2)
// ---------------------------------------------------------------------------
__global__ __launch_bounds__(256) void stats_kernel(
    const u16* __restrict__ ft, const u16* __restrict__ gt,
    float* __restrict__ L) {
  __shared__ float zred[32][64];
  const int t = threadIdx.x, w = t >> 6, l = t & 63, li = l & 15, q = l >> 4;
  const int n0 = blockIdx.x * 32;
  const int bb = blockIdx.z * 4 + blockIdx.y;
  const u16* ftb = ft + (size_t)bb * NDIM * KD;
  const u16* gtb = gt + (size_t)bb * NDIM * KD;
  f32x4 zero4 = {0.f, 0.f, 0.f, 0.f};

  short8 a0 = *(const short8*)&ftb[(size_t)(n0 + li) * KD + q * 8];
  short8 a1 = *(const short8*)&ftb[(size_t)(n0 + 16 + li) * KD + q * 8];
  f32x4 z0 = zero4, z1 = zero4;

#pragma unroll 2
  for (int it = 0; it < 64; it++) {
    int m = (it * 4 + w) * 16;
    short8 bf = *(const short8*)&gtb[(size_t)(m + li) * KD + q * 8];
    f32x4 S0 = MFMA16(a0, bf, zero4);
    f32x4 S1 = MFMA16(a1, bf, zero4);
#pragma unroll
    for (int reg = 0; reg < 4; reg++) {
      z0[reg] += __expf(S0[reg] * SCALE - SHIFT);
      z1[reg] += __expf(S1[reg] * SCALE - SHIFT);
    }
  }
#pragma unroll
  for (int reg = 0; reg < 4; reg++) {
    zred[q * 4 + reg][w * 16 + li] = z0[reg];
    zred[16 + q * 4 + reg][w * 16 + li] = z1[reg];
  }
  __syncthreads();
  const int r = t >> 3, i8 = t & 7;
  float4 s1 = *(const float4*)&zred[r][i8 * 8];
  float4 s2 = *(const float4*)&zred[r][i8 * 8 + 4];
  float sum = s1.x + s1.y + s1.z + s1.w + s2.x + s2.y + s2.z + s2.w;
  sum += __shfl_xor(sum, 1, 8);
  sum += __shfl_xor(sum, 2, 8);
  sum += __shfl_xor(sum, 4, 8);
  if (i8 == 0) L[(size_t)bb * NDIM + n0 + r] = SHIFT + __logf(sum);
}

// ---------------------------------------------------------------------------
// apply: out[c][m] = gamma * sum_n h[c,n]*exp(s[n,m]-L[n]) + x[c][m]
// block 512 (8 waves), m-tile 64, full C=256, K-loop n in chunks of 32.
// Phase A (all 8 waves = 8 score subtiles): MFMA scores, exp, Pt to LDS.
// Phase B: wave w owns c in [w*32, w*32+32): 8 MFMAs vs Pt.
// h/ft frags read straight from global (L2-hot, dense-1KB patterns).
// grid (64, 4, 2)
// ---------------------------------------------------------------------------
__global__ __launch_bounds__(512, 4) void apply_kernel(
    const u16* __restrict__ ft, const u16* __restrict__ gt,
    const u16* __restrict__ h, const float* __restrict__ L,
    const float* __restrict__ x1, const float* __restrict__ x2,
    const float* __restrict__ gamma1, const float* __restrict__ gamma2,
    float* __restrict__ out) {
  __shared__ u16 Pt[64][32];  // P^T[m][n-chunk] bf16
  const int t = threadIdx.x, w = t >> 6, l = t & 63, li = l & 15, q = l >> 4;
  const int mtile = blockIdx.x * 64;
  const int b = blockIdx.y, br = blockIdx.z, bb = br * 4 + b;
  const u16* ftb = ft + (size_t)bb * NDIM * KD;
  const u16* gtb = gt + (size_t)bb * NDIM * KD;
  const u16* hb = h + (size_t)bb * CDIM * NDIM;
  const float* Lb = L + (size_t)bb * NDIM;
  const float* xb = (br ? x2 : x1) + (size_t)b * CDIM * NDIM;
  const float gmv = br ? gamma2[0] : gamma1[0];
  float* ob = out + (size_t)bb * CDIM * NDIM;

  const int nsub = w & 1, msub = w >> 1;  // phase-A score subtile
  const int c0 = w * 32;                  // phase-B c range
  f32x4 zero4 = {0.f, 0.f, 0.f, 0.f};
  short8 gfrag = *(const short8*)&gtb[(size_t)(mtile + msub * 16 + li) * KD + q * 8];

  f32x4 acc[2][4];
  for (int i = 0; i < 2; i++) for (int j = 0; j < 4; j++) acc[i][j] = zero4;

  for (int n0 = 0; n0 < NDIM; n0 += 32) {
    // global loads first (overlap latency with barrier of previous iter)
    short8 af = *(const short8*)&ftb[(size_t)(n0 + nsub * 16 + li) * KD + q * 8];
    f32x4 L4 = *(const f32x4*)&Lb[n0 + nsub * 16 + q * 4];
    short8 ah0 = *(const short8*)&hb[(size_t)(c0 + li) * NDIM + n0 + q * 8];
    short8 ah1 = *(const short8*)&hb[(size_t)(c0 + 16 + li) * NDIM + n0 + q * 8];

    f32x4 S = MFMA16(af, gfrag, zero4);
    u32 p0 = f2bf(__expf(S[0] * SCALE - L4[0])) |
             (f2bf(__expf(S[1] * SCALE - L4[1])) << 16);
    u32 p1 = f2bf(__expf(S[2] * SCALE - L4[2])) |
             (f2bf(__expf(S[3] * SCALE - L4[3])) << 16);

    __syncthreads();  // previous-iter Pt reads complete
    *(uint2*)&Pt[msub * 16 + li][nsub * 16 + q * 4] = make_uint2(p0, p1);
    __syncthreads();  // Pt published

#pragma unroll
    for (int ms = 0; ms < 4; ms++) {
      short8 bm = *(const short8*)&Pt[ms * 16 + li][q * 8];
      acc[0][ms] = MFMA16(ah0, bm, acc[0][ms]);
      acc[1][ms] = MFMA16(ah1, bm, acc[1][ms]);
    }
  }

#pragma unroll
  for (int cs = 0; cs < 2; cs++) {
#pragma unroll
    for (int ms = 0; ms < 4; ms++) {
#pragma unroll
      for (int reg = 0; reg < 4; reg++) {
        int c = c0 + cs * 16 + q * 4 + reg;
        int m = mtile + ms * 16 + li;
        size_t idx = (size_t)c * NDIM + m;
        ob[idx] = gmv * acc[cs][ms][reg] + xb[idx];
      }
    }
  }
}

// ---------------------------------------------------------------------------
extern "C" void kernel_launch(void* const* d_in, const int* in_sizes, int n_in,
                              void* d_out, int out_size, void* d_ws, size_t ws_size,
                              hipStream_t stream) {
  const float* x1 = (const float*)d_in[0];
  const float* x2 = (const float*)d_in[1];
  const float* f_w = (const float*)d_in[2];
  const float* f_b = (const float*)d_in[3];
  const float* g_w = (const float*)d_in[4];
  const float* g_b = (const float*)d_in[5];
  const float* h1_w = (const float*)d_in[6];
  const float* h1_b = (const float*)d_in[7];
  const float* h2_w = (const float*)d_in[8];
  const float* h2_b = (const float*)d_in[9];
  const float* gamma1 = (const float*)d_in[10];
  const float* gamma2 = (const float*)d_in[11];
  float* out = (float*)d_out;

  char* ws = (char*)d_ws;
  u16* xt  = (u16*)(ws);                          // [8][4096][256]  16 MB
  u16* wh  = (u16*)(ws + 16777216);               // [8][256][4096]  16 MB
  u16* ftw = (u16*)(ws + 33554432);               // [8][4096][32]    2 MB
  u16* gtw = (u16*)(ws + 35651584);               // [8][4096][32]    2 MB
  u16* wWh = (u16*)(ws + 37748736);               // [2][256][256]  256 KB
  u16* wWf = (u16*)(ws + 38010880);               // [32][256]       16 KB
  u16* wWg = (u16*)(ws + 38027264);               // [32][256]       16 KB
  float* Lw = (float*)(ws + 38043648);            // [8][4096]      128 KB

  cast_bf16_kernel<<<256, 256, 0, stream>>>(h1_w, wWh, 65536);
  cast_bf16_kernel<<<256, 256, 0, stream>>>(h2_w, wWh + 65536, 65536);
  cast_bf16_kernel<<<32, 256, 0, stream>>>(f_w, wWf, 8192);
  cast_bf16_kernel<<<32, 256, 0, stream>>>(g_w, wWg, 8192);

  transpose_cast_kernel<<<dim3(64, 4, 8), 256, 0, stream>>>(x1, x2, xt);

  conv_fg_kernel<<<dim3(32, 8), 256, 0, stream>>>(wWf, f_b, xt, ftw);
  conv_fg_kernel<<<dim3(32, 8), 256, 0, stream>>>(wWg, g_b, xt, gtw);
  conv_h_kernel<<<dim3(64, 4, 4), 256, 0, stream>>>(wWh, h1_b, xt, wh);
  conv_h_kernel<<<dim3(64, 4, 4), 256, 0, stream>>>(
      wWh + 65536, h2_b, xt + (size_t)4 * NDIM * CDIM, wh + (size_t)4 * CDIM * NDIM);

  stats_kernel<<<dim3(128, 4, 2), 256, 0, stream>>>(ftw, gtw, Lw);

  apply_kernel<<<dim3(64, 4, 2), 512, 0, stream>>>(ftw, gtw, wh, Lw, x1, x2,
                                                   gamma1, gamma2, out);
}